// Round 10
// baseline (175.023 us; speedup 1.0000x reference)
//
#include <hip/hip_runtime.h>
#include <hip/hip_bf16.h>

// x (16,1024,512) fp32 -> d = max(0, sq_i+sq_j-2*X X^T) per batch
// -> global-mean/var LayerNorm -> softmax(-(d_hat*gamma+beta)/TEMP, axis=-1).
// Softmax shift-invariance => mean & beta cancel; scale = gamma*rsqrt(var+eps)/TEMP.
// var needs global sum(d),sum(d^2) in f64. Row-shift-invariance => d'=d-sq_row fp16.
//
// gram8: NO LDS STAGING. Fragments read directly from global; per-XCD slab
// (2 batches = 2MB bf16) is L2-resident because sqcvt is XCD-aligned with
// gram's batch map (producer/consumer same L2). K-loop = pure loads+MFMA,
// compiler-pipelined; zero barriers. (Guide: staging L2-fit data is pure
// overhead, m169/m233 — 4 staged-schedule variants all nulled at ~35us.)

#define S_DIM 1024
#define E_DIM 512
#define NBATCH 16
#define TEMP_C 13.544

typedef __attribute__((ext_vector_type(4))) float f32x4;
typedef __attribute__((ext_vector_type(8))) short bf16x8;
typedef __attribute__((ext_vector_type(8))) _Float16 f16x8;

__device__ inline unsigned pkbf(float lo, float hi) {
  unsigned a = __float_as_uint(lo), b = __float_as_uint(hi);
  a = (a + 0x7FFFu + ((a >> 16) & 1u)) >> 16;          // RNE bf16 of lo
  b = (b + 0x7FFFu + ((b >> 16) & 1u)) & 0xFFFF0000u;  // RNE bf16 of hi << 16
  return b | a;
}

// ------ Kernel 1: fp32->bf16 + row square-sums, XCD-aligned with gram ------
// bid: xcd=bid&7, li=bid>>3 in [0,512). Rows [xcd*2048 + li*4, +4): XCD x
// produces exactly the slabs (batches 2x,2x+1) that gram blocks on XCD x read.
__global__ __launch_bounds__(256) void sqcvt(const float* __restrict__ x,
                                             ushort* __restrict__ xb16,
                                             float* __restrict__ sq,
                                             double* __restrict__ sums) {
  const int wave = threadIdx.x >> 6, lane = threadIdx.x & 63;
  const int xcd = blockIdx.x & 7, li = blockIdx.x >> 3;
  const size_t row = (size_t)xcd * 2048 + (size_t)li * 4 + wave;
  const float4* xr = reinterpret_cast<const float4*>(x + row * E_DIM);
  float4 a = xr[lane * 2], b = xr[lane * 2 + 1];
  uint4 p;
  p.x = pkbf(a.x, a.y); p.y = pkbf(a.z, a.w);
  p.z = pkbf(b.x, b.y); p.w = pkbf(b.z, b.w);
  *reinterpret_cast<uint4*>(xb16 + row * E_DIM + lane * 8) = p;
  float s = a.x*a.x + a.y*a.y + a.z*a.z + a.w*a.w +
            b.x*b.x + b.y*b.y + b.z*b.z + b.w*b.w;
#pragma unroll
  for (int o = 32; o > 0; o >>= 1) s += __shfl_xor(s, o);
  if (lane == 0) sq[row] = s;
  if (blockIdx.x == 0 && threadIdx.x == 0) { sums[0] = 0.0; sums[1] = 0.0; }
}

// ---------- Kernel 2: 256^2-tile gram, LDS-free, L2-direct fragments --------
// 8 waves (2x4): wave (wr,wc) owns 128x64 of the 256x256 tile; acc[8][4]
// f32x4 frags of 16x16x32. Per K-step: 8 A-frag + 4 B-frag global_load_dwordx4
// (L2-hot; L1 serves the cross-wave re-reads) + 32 MFMA. No barriers in loop.
// MODE 0: d fp32 -> dout.  MODE 1: d' = d - sq_row fp16 -> dp.
template <int MODE>
__global__ __launch_bounds__(512) void gram8(const ushort* __restrict__ xb16,
                                             const float* __restrict__ sq,
                                             float* __restrict__ dout,
                                             _Float16* __restrict__ dp,
                                             double* __restrict__ sums) {
  __shared__ double red[16];

  const int tid = threadIdx.x, wave = tid >> 6, lane = tid & 63;
  const int wr = wave >> 2, wc = wave & 3;

  // 1 block/CU; 32 blocks/XCD; batches 2x,2x+1 on XCD x (slab L2-resident).
  const int bid = blockIdx.x;
  const int xcd = bid & 7, j = bid >> 3;            // j = 0..31
  const int b = xcd * 2 + (j >> 4);
  const int tile = j & 15;
  const int tr = tile >> 2, tc = tile & 3;

  const ushort* xb = xb16 + (size_t)b * (S_DIM * E_DIM);
  const int rowA0 = tr * 256, rowB0 = tc * 256;

  // Fragment base addrs (bytes): row = rowX0 + w*{128,64} + m*16 + (lane&15),
  // k-chunk = (lane>>4)*8 bf16 = 16B. Row stride = E_DIM*2 = 1024 B.
  const char* Abase = (const char*)(xb + (size_t)(rowA0 + wr * 128 + (lane & 15)) * E_DIM)
                      + (lane >> 4) * 16;
  const char* Bbase = (const char*)(xb + (size_t)(rowB0 + wc * 64 + (lane & 15)) * E_DIM)
                      + (lane >> 4) * 16;

  f32x4 acc[8][4] = {};

#pragma unroll 2
  for (int ks = 0; ks < E_DIM / 32; ++ks) {
    const int ko = ks * 64;            // 32 bf16 = 64 bytes per K-step
    bf16x8 af[8], bfr[4];
#pragma unroll
    for (int m = 0; m < 8; ++m)
      af[m] = *reinterpret_cast<const bf16x8*>(Abase + (size_t)m * 16 * 1024 + ko);
#pragma unroll
    for (int n = 0; n < 4; ++n)
      bfr[n] = *reinterpret_cast<const bf16x8*>(Bbase + (size_t)n * 16 * 1024 + ko);
#pragma unroll
    for (int m = 0; m < 8; ++m)
#pragma unroll
      for (int n = 0; n < 4; ++n)
        acc[m][n] = __builtin_amdgcn_mfma_f32_16x16x32_bf16(af[m], bfr[n], acc[m][n], 0, 0, 0);
  }

  // Epilogue. C/D layout: col=lane&15, row=(lane>>4)*4+reg.
  const float* sqb = sq + b * S_DIM;
  double sd = 0.0, sd2 = 0.0;
#pragma unroll
  for (int m = 0; m < 8; ++m) {
    int gr0 = tr * 256 + wr * 128 + m * 16 + ((lane >> 4) << 2);
    float sqr0 = sqb[gr0], sqr1 = sqb[gr0 + 1], sqr2 = sqb[gr0 + 2], sqr3 = sqb[gr0 + 3];
#pragma unroll
    for (int n = 0; n < 4; ++n) {
      int gc = tc * 256 + wc * 64 + n * 16 + (lane & 15);
      float sqc = sqb[gc];
      float d0 = fmaxf(sqr0 + sqc - 2.0f * acc[m][n][0], 0.0f);
      float d1 = fmaxf(sqr1 + sqc - 2.0f * acc[m][n][1], 0.0f);
      float d2 = fmaxf(sqr2 + sqc - 2.0f * acc[m][n][2], 0.0f);
      float d3 = fmaxf(sqr3 + sqc - 2.0f * acc[m][n][3], 0.0f);
      if (MODE == 0) {
        float* dbase = dout + (size_t)b * S_DIM * S_DIM;
        dbase[(size_t)(gr0 + 0) * S_DIM + gc] = d0;
        dbase[(size_t)(gr0 + 1) * S_DIM + gc] = d1;
        dbase[(size_t)(gr0 + 2) * S_DIM + gc] = d2;
        dbase[(size_t)(gr0 + 3) * S_DIM + gc] = d3;
      } else {
        _Float16* dbase = dp + (size_t)b * S_DIM * S_DIM;
        dbase[(size_t)(gr0 + 0) * S_DIM + gc] = (_Float16)(d0 - sqr0);
        dbase[(size_t)(gr0 + 1) * S_DIM + gc] = (_Float16)(d1 - sqr1);
        dbase[(size_t)(gr0 + 2) * S_DIM + gc] = (_Float16)(d2 - sqr2);
        dbase[(size_t)(gr0 + 3) * S_DIM + gc] = (_Float16)(d3 - sqr3);
      }
      sd += (double)d0 + (double)d1 + (double)d2 + (double)d3;
      sd2 += (double)d0 * d0 + (double)d1 * d1 + (double)d2 * d2 + (double)d3 * d3;
    }
  }
#pragma unroll
  for (int o = 32; o > 0; o >>= 1) {
    sd += __shfl_xor(sd, o);
    sd2 += __shfl_xor(sd2, o);
  }
  if (lane == 0) { red[wave] = sd; red[8 + wave] = sd2; }
  __syncthreads();
  if (tid == 0) {
    double t1 = 0.0, t2 = 0.0;
#pragma unroll
    for (int w = 0; w < 8; ++w) { t1 += red[w]; t2 += red[8 + w]; }
    atomicAdd(&sums[0], t1);
    atomicAdd(&sums[1], t2);
  }
}

__device__ inline float ln_scale(const double* sums, const float* gamma) {
  constexpr double invN = 1.0 / (16.0 * 1024.0 * 1024.0);
  double mean = sums[0] * invN;
  double var = sums[1] * invN - mean * mean;
  return (float)(-((double)gamma[0]) / (sqrt(var + 1e-5) * TEMP_C));
}

// ---------------- Kernel 3a: softmax from fp32 d (in-place in dout) ---------
__global__ __launch_bounds__(256) void softmax_f32(float* __restrict__ d,
                                                   const double* __restrict__ sums,
                                                   const float* __restrict__ gamma) {
  const int wave = threadIdx.x >> 6, lane = threadIdx.x & 63;
  const int xcd = blockIdx.x & 7, li = blockIdx.x >> 3;
  const size_t row = (size_t)xcd * 2048 + (size_t)li * 4 + wave;
  const float scale = ln_scale(sums, gamma);
  float4* r4 = reinterpret_cast<float4*>(d + row * S_DIM);
  float4 v[4];
#pragma unroll
  for (int i = 0; i < 4; ++i) v[i] = r4[lane + 64 * i];
  float l[16];
#pragma unroll
  for (int i = 0; i < 4; ++i) {
    l[4*i+0] = scale * v[i].x; l[4*i+1] = scale * v[i].y;
    l[4*i+2] = scale * v[i].z; l[4*i+3] = scale * v[i].w;
  }
  float mx = l[0];
#pragma unroll
  for (int i = 1; i < 16; ++i) mx = fmaxf(mx, l[i]);
#pragma unroll
  for (int o = 32; o > 0; o >>= 1) mx = fmaxf(mx, __shfl_xor(mx, o));
  const float L2E = 1.4426950408889634f;
  float e[16], s = 0.f;
#pragma unroll
  for (int i = 0; i < 16; ++i) { e[i] = exp2f((l[i] - mx) * L2E); s += e[i]; }
#pragma unroll
  for (int o = 32; o > 0; o >>= 1) s += __shfl_xor(s, o);
  float inv = 1.0f / s;
#pragma unroll
  for (int i = 0; i < 4; ++i)
    r4[lane + 64 * i] = make_float4(e[4*i]*inv, e[4*i+1]*inv, e[4*i+2]*inv, e[4*i+3]*inv);
}

// ------- Kernel 3b: softmax from fp16 d' -> fp32 out, XCD-aligned ----------
__global__ __launch_bounds__(256) void softmax_f16(const _Float16* __restrict__ dp,
                                                   float* __restrict__ out,
                                                   const double* __restrict__ sums,
                                                   const float* __restrict__ gamma) {
  const int wave = threadIdx.x >> 6, lane = threadIdx.x & 63;
  const int xcd = blockIdx.x & 7, li = blockIdx.x >> 3;
  const size_t row = (size_t)xcd * 2048 + (size_t)li * 4 + wave;
  const float scale = ln_scale(sums, gamma);
  const f16x8* r8 = reinterpret_cast<const f16x8*>(dp + row * S_DIM);
  f16x8 h0 = r8[lane * 2], h1 = r8[lane * 2 + 1];
  float l[16];
#pragma unroll
  for (int i = 0; i < 8; ++i) { l[i] = scale * (float)h0[i]; l[8 + i] = scale * (float)h1[i]; }
  float mx = l[0];
#pragma unroll
  for (int i = 1; i < 16; ++i) mx = fmaxf(mx, l[i]);
#pragma unroll
  for (int o = 32; o > 0; o >>= 1) mx = fmaxf(mx, __shfl_xor(mx, o));
  const float L2E = 1.4426950408889634f;
  float e[16], s = 0.f;
#pragma unroll
  for (int i = 0; i < 16; ++i) { e[i] = exp2f((l[i] - mx) * L2E); s += e[i]; }
#pragma unroll
  for (int o = 32; o > 0; o >>= 1) s += __shfl_xor(s, o);
  float inv = 1.0f / s;
  float4* o4 = reinterpret_cast<float4*>(out + row * S_DIM);
#pragma unroll
  for (int i = 0; i < 4; ++i)
    o4[lane * 4 + i] = make_float4(e[4*i]*inv, e[4*i+1]*inv, e[4*i+2]*inv, e[4*i+3]*inv);
}

extern "C" void kernel_launch(void* const* d_in, const int* in_sizes, int n_in,
                              void* d_out, int out_size, void* d_ws, size_t ws_size,
                              hipStream_t stream) {
  const float* x = (const float*)d_in[0];
  const float* gamma = (const float*)d_in[1];
  float* out = (float*)d_out;
  double* sums = (double*)d_ws;                              // 2 doubles @0
  float* sq = (float*)((char*)d_ws + 256);                   // 16384 floats
  ushort* xb16 = (ushort*)((char*)d_ws + 256 + 65536);       // 16 MB bf16 x
  _Float16* dp = (_Float16*)((char*)d_ws + 256 + 65536 +
                             (size_t)NBATCH * S_DIM * E_DIM * 2);  // 32 MB fp16 d'
  const size_t need_b = 256 + 65536 + (size_t)NBATCH * S_DIM * E_DIM * 2;
  const size_t need_a = need_b + (size_t)NBATCH * S_DIM * S_DIM * 2;

  sqcvt<<<dim3(NBATCH * S_DIM / 4), dim3(256), 0, stream>>>(x, xb16, sq, sums);
  if (ws_size >= need_a) {
    gram8<1><<<dim3(256), dim3(512), 0, stream>>>(xb16, sq, out, dp, sums);
    softmax_f16<<<dim3(NBATCH * S_DIM / 4), dim3(256), 0, stream>>>(dp, out, sums, gamma);
  } else {
    gram8<0><<<dim3(256), dim3(512), 0, stream>>>(xb16, sq, out, dp, sums);
    softmax_f32<<<dim3(NBATCH * S_DIM / 4), dim3(256), 0, stream>>>(out, sums, gamma);
  }
}

// Round 11
// 148.516 us; speedup vs baseline: 1.1785x; 1.1785x over previous
//
#include <hip/hip_runtime.h>
#include <hip/hip_bf16.h>

// x (16,1024,512) fp32 -> d = max(0, sq_i+sq_j-2*X X^T) per batch
// -> global-mean/var LayerNorm -> softmax(-(d_hat*gamma+beta)/TEMP, axis=-1).
// Softmax shift-invariance => mean & beta cancel; scale = gamma*rsqrt(var+eps)/TEMP.
// var needs global sum(d),sum(d^2) in f64. Row-shift-invariance => d'=d-sq_row fp16.
//
// gram9: m201-style fine-phase schedule on the gram5 geometry.
// 256^2 tile, 8 waves (2Mx4N), K-tile=64 (8 tiles), 4 quadrant-phases/tile:
//   phase: [stage 1 half-tile of tile kt+1] [vmcnt(2) @phase0] barrier
//          [ds_read quadrant frags] setprio(1) 16 MFMA setprio(0) barrier
// 2 LDS buffers (128KB), halves: {A-h0,A-h1,B-h0,B-h1} 16KB each, staged one
// per phase into buf^1 (WAR-safe: buf^1 readers done before prev barrier).
// Counted vmcnt(2) once per K-tile (never 0 mid-loop). 8-slot XOR swizzle
// slot^(row&7) (bank-balanced), pre-applied to global source (rule 21).

#define S_DIM 1024
#define E_DIM 512
#define NBATCH 16
#define TEMP_C 13.544

typedef __attribute__((ext_vector_type(4))) float f32x4;
typedef __attribute__((ext_vector_type(8))) short bf16x8;
typedef __attribute__((ext_vector_type(8))) _Float16 f16x8;

__device__ inline unsigned pkbf(float lo, float hi) {
  unsigned a = __float_as_uint(lo), b = __float_as_uint(hi);
  a = (a + 0x7FFFu + ((a >> 16) & 1u)) >> 16;          // RNE bf16 of lo
  b = (b + 0x7FFFu + ((b >> 16) & 1u)) & 0xFFFF0000u;  // RNE bf16 of hi << 16
  return b | a;
}

__device__ inline void gload16(const void* g, void* l) {
  __builtin_amdgcn_global_load_lds(
      (const __attribute__((address_space(1))) unsigned*)g,
      (__attribute__((address_space(3))) unsigned*)l, 16, 0, 0);
}

// ------ Kernel 1: fp32->bf16 + row square-sums, XCD-aligned with gram ------
__global__ __launch_bounds__(256) void sqcvt(const float* __restrict__ x,
                                             ushort* __restrict__ xb16,
                                             float* __restrict__ sq,
                                             double* __restrict__ sums) {
  const int wave = threadIdx.x >> 6, lane = threadIdx.x & 63;
  const int xcd = blockIdx.x & 7, li = blockIdx.x >> 3;
  const size_t row = (size_t)xcd * 2048 + (size_t)li * 4 + wave;
  const float4* xr = reinterpret_cast<const float4*>(x + row * E_DIM);
  float4 a = xr[lane * 2], b = xr[lane * 2 + 1];
  uint4 p;
  p.x = pkbf(a.x, a.y); p.y = pkbf(a.z, a.w);
  p.z = pkbf(b.x, b.y); p.w = pkbf(b.z, b.w);
  *reinterpret_cast<uint4*>(xb16 + row * E_DIM + lane * 8) = p;
  float s = a.x*a.x + a.y*a.y + a.z*a.z + a.w*a.w +
            b.x*b.x + b.y*b.y + b.z*b.z + b.w*b.w;
#pragma unroll
  for (int o = 32; o > 0; o >>= 1) s += __shfl_xor(s, o);
  if (lane == 0) sq[row] = s;
  if (blockIdx.x == 0 && threadIdx.x == 0) { sums[0] = 0.0; sums[1] = 0.0; }
}

// ---------------- Kernel 2: gram, m201-style 4-phase K-tiles ----------------
// LDS tile layout: [buf][half(128 rows)][row][64 K bf16]; 16B slot s of row r
// holds logical k-slot s^(r&7). Fragment read: phys = (ks*4+(lane>>4))^(r&7).
template <int MODE>
__global__ __launch_bounds__(512) void gram9(const ushort* __restrict__ xb16,
                                             const float* __restrict__ sq,
                                             float* __restrict__ dout,
                                             _Float16* __restrict__ dp,
                                             double* __restrict__ sums) {
  __shared__ ushort lA[2][2][128][64];   // 64 KB
  __shared__ ushort lB[2][2][128][64];   // 64 KB
  __shared__ double red[16];

  const int tid = threadIdx.x, wave = tid >> 6, lane = tid & 63;
  const int wr = wave >> 2, wc = wave & 3;

  const int bid = blockIdx.x;
  const int xcd = bid & 7, j = bid >> 3;
  const int b = xcd * 2 + (j >> 4);
  const int tile = j & 15;
  const int tr = tile >> 2, tc = tile & 3;

  const ushort* xb = xb16 + (size_t)b * (S_DIM * E_DIM);
  const int rowA0 = tr * 256, rowB0 = tc * 256;

  // Per-thread pre-swizzled global offsets for the 2 slots of a 16KB half.
  int eA[2], eB[2];
#pragma unroll
  for (int i = 0; i < 2; ++i) {
    int p = i * 512 + tid;          // 16B slot in half
    int r = p >> 3;                 // row in half (0..127)
    int sl = (p & 7) ^ (r & 7);     // logical k-slot
    eA[i] = (rowA0 + r) * E_DIM + sl * 8;
    eB[i] = (rowB0 + r) * E_DIM + sl * 8;
  }

  // idx: 0=A-h0 1=A-h1 2=B-h0 3=B-h1; dest buf = kt&1.
  auto stage = [&](int kt, int idx) {
    const int buf = kt & 1, h = idx & 1;
    const int off = h * 128 * E_DIM + kt * 64;
    if (idx < 2) {
      char* dst = (char*)&lA[buf][h][0][0];
      gload16(xb + eA[0] + off, dst + tid * 16);
      gload16(xb + eA[1] + off, dst + 8192 + tid * 16);
    } else {
      char* dst = (char*)&lB[buf][h][0][0];
      gload16(xb + eB[0] + off, dst + tid * 16);
      gload16(xb + eB[1] + off, dst + 8192 + tid * 16);
    }
  };

  f32x4 acc[8][4] = {};
  bf16x8 af[4][2], bfr[2][2];

  stage(0, 0); stage(0, 1); stage(0, 2); stage(0, 3);

#pragma unroll 1
  for (int kt = 0; kt < 8; ++kt) {
    const char* la = (const char*)&lA[kt & 1][0][0][0];
    const char* lb = (const char*)&lB[kt & 1][0][0][0];
#pragma unroll
    for (int ph = 0; ph < 4; ++ph) {
      const int mq = ph >> 1, nq = ph & 1;
      if (kt < 7) stage(kt + 1, ph);          // -> buf^1 (readers done, WAR-safe)
      if (ph == 0) {
        if (kt < 7) asm volatile("s_waitcnt vmcnt(2)" ::: "memory");  // tile kt landed
        else        asm volatile("s_waitcnt vmcnt(0)" ::: "memory");
      }
      __builtin_amdgcn_s_barrier();
      __builtin_amdgcn_sched_barrier(0);

      if (nq == 0) {                          // (mq,0): load A quadrant frags
#pragma unroll
        for (int mf = 0; mf < 4; ++mf)
#pragma unroll
          for (int ks = 0; ks < 2; ++ks) {
            int row = wr * 128 + mq * 64 + mf * 16 + (lane & 15);
            int half = row >> 7, r = row & 127;
            int sl = (ks * 4 + (lane >> 4)) ^ (r & 7);
            af[mf][ks] = *reinterpret_cast<const bf16x8*>(la + half * 16384 + r * 128 + sl * 16);
          }
      }
#pragma unroll
      for (int nf = 0; nf < 2; ++nf)
#pragma unroll
        for (int ks = 0; ks < 2; ++ks) {
          int row = wc * 64 + nq * 32 + nf * 16 + (lane & 15);
          int half = row >> 7, r = row & 127;
          int sl = (ks * 4 + (lane >> 4)) ^ (r & 7);
          bfr[nf][ks] = *reinterpret_cast<const bf16x8*>(lb + half * 16384 + r * 128 + sl * 16);
        }

      __builtin_amdgcn_s_setprio(1);
#pragma unroll
      for (int ks = 0; ks < 2; ++ks)
#pragma unroll
        for (int mf = 0; mf < 4; ++mf)
#pragma unroll
          for (int nf = 0; nf < 2; ++nf)
            acc[mq * 4 + mf][nq * 2 + nf] = __builtin_amdgcn_mfma_f32_16x16x32_bf16(
                af[mf][ks], bfr[nf][ks], acc[mq * 4 + mf][nq * 2 + nf], 0, 0, 0);
      __builtin_amdgcn_s_setprio(0);
      __builtin_amdgcn_s_barrier();
    }
  }

  // Epilogue. C/D layout: col=lane&15, row=(lane>>4)*4+reg.
  const float* sqb = sq + b * S_DIM;
  double sd = 0.0, sd2 = 0.0;
#pragma unroll
  for (int m = 0; m < 8; ++m) {
    int gr0 = tr * 256 + wr * 128 + m * 16 + ((lane >> 4) << 2);
    float sqr0 = sqb[gr0], sqr1 = sqb[gr0 + 1], sqr2 = sqb[gr0 + 2], sqr3 = sqb[gr0 + 3];
#pragma unroll
    for (int n = 0; n < 4; ++n) {
      int gc = tc * 256 + wc * 64 + n * 16 + (lane & 15);
      float sqc = sqb[gc];
      float d0 = fmaxf(sqr0 + sqc - 2.0f * acc[m][n][0], 0.0f);
      float d1 = fmaxf(sqr1 + sqc - 2.0f * acc[m][n][1], 0.0f);
      float d2 = fmaxf(sqr2 + sqc - 2.0f * acc[m][n][2], 0.0f);
      float d3 = fmaxf(sqr3 + sqc - 2.0f * acc[m][n][3], 0.0f);
      if (MODE == 0) {
        float* dbase = dout + (size_t)b * S_DIM * S_DIM;
        dbase[(size_t)(gr0 + 0) * S_DIM + gc] = d0;
        dbase[(size_t)(gr0 + 1) * S_DIM + gc] = d1;
        dbase[(size_t)(gr0 + 2) * S_DIM + gc] = d2;
        dbase[(size_t)(gr0 + 3) * S_DIM + gc] = d3;
      } else {
        _Float16* dbase = dp + (size_t)b * S_DIM * S_DIM;
        dbase[(size_t)(gr0 + 0) * S_DIM + gc] = (_Float16)(d0 - sqr0);
        dbase[(size_t)(gr0 + 1) * S_DIM + gc] = (_Float16)(d1 - sqr1);
        dbase[(size_t)(gr0 + 2) * S_DIM + gc] = (_Float16)(d2 - sqr2);
        dbase[(size_t)(gr0 + 3) * S_DIM + gc] = (_Float16)(d3 - sqr3);
      }
      sd += (double)d0 + (double)d1 + (double)d2 + (double)d3;
      sd2 += (double)d0 * d0 + (double)d1 * d1 + (double)d2 * d2 + (double)d3 * d3;
    }
  }
#pragma unroll
  for (int o = 32; o > 0; o >>= 1) {
    sd += __shfl_xor(sd, o);
    sd2 += __shfl_xor(sd2, o);
  }
  if (lane == 0) { red[wave] = sd; red[8 + wave] = sd2; }
  __syncthreads();
  if (tid == 0) {
    double t1 = 0.0, t2 = 0.0;
#pragma unroll
    for (int w = 0; w < 8; ++w) { t1 += red[w]; t2 += red[8 + w]; }
    atomicAdd(&sums[0], t1);
    atomicAdd(&sums[1], t2);
  }
}

__device__ inline float ln_scale(const double* sums, const float* gamma) {
  constexpr double invN = 1.0 / (16.0 * 1024.0 * 1024.0);
  double mean = sums[0] * invN;
  double var = sums[1] * invN - mean * mean;
  return (float)(-((double)gamma[0]) / (sqrt(var + 1e-5) * TEMP_C));
}

// ---------------- Kernel 3a: softmax from fp32 d (in-place in dout) ---------
__global__ __launch_bounds__(256) void softmax_f32(float* __restrict__ d,
                                                   const double* __restrict__ sums,
                                                   const float* __restrict__ gamma) {
  const int wave = threadIdx.x >> 6, lane = threadIdx.x & 63;
  const int xcd = blockIdx.x & 7, li = blockIdx.x >> 3;
  const size_t row = (size_t)xcd * 2048 + (size_t)li * 4 + wave;
  const float scale = ln_scale(sums, gamma);
  float4* r4 = reinterpret_cast<float4*>(d + row * S_DIM);
  float4 v[4];
#pragma unroll
  for (int i = 0; i < 4; ++i) v[i] = r4[lane + 64 * i];
  float l[16];
#pragma unroll
  for (int i = 0; i < 4; ++i) {
    l[4*i+0] = scale * v[i].x; l[4*i+1] = scale * v[i].y;
    l[4*i+2] = scale * v[i].z; l[4*i+3] = scale * v[i].w;
  }
  float mx = l[0];
#pragma unroll
  for (int i = 1; i < 16; ++i) mx = fmaxf(mx, l[i]);
#pragma unroll
  for (int o = 32; o > 0; o >>= 1) mx = fmaxf(mx, __shfl_xor(mx, o));
  const float L2E = 1.4426950408889634f;
  float e[16], s = 0.f;
#pragma unroll
  for (int i = 0; i < 16; ++i) { e[i] = exp2f((l[i] - mx) * L2E); s += e[i]; }
#pragma unroll
  for (int o = 32; o > 0; o >>= 1) s += __shfl_xor(s, o);
  float inv = 1.0f / s;
#pragma unroll
  for (int i = 0; i < 4; ++i)
    r4[lane + 64 * i] = make_float4(e[4*i]*inv, e[4*i+1]*inv, e[4*i+2]*inv, e[4*i+3]*inv);
}

// ------- Kernel 3b: softmax from fp16 d' -> fp32 out, XCD-aligned ----------
__global__ __launch_bounds__(256) void softmax_f16(const _Float16* __restrict__ dp,
                                                   float* __restrict__ out,
                                                   const double* __restrict__ sums,
                                                   const float* __restrict__ gamma) {
  const int wave = threadIdx.x >> 6, lane = threadIdx.x & 63;
  const int xcd = blockIdx.x & 7, li = blockIdx.x >> 3;
  const size_t row = (size_t)xcd * 2048 + (size_t)li * 4 + wave;
  const float scale = ln_scale(sums, gamma);
  const f16x8* r8 = reinterpret_cast<const f16x8*>(dp + row * S_DIM);
  f16x8 h0 = r8[lane * 2], h1 = r8[lane * 2 + 1];
  float l[16];
#pragma unroll
  for (int i = 0; i < 8; ++i) { l[i] = scale * (float)h0[i]; l[8 + i] = scale * (float)h1[i]; }
  float mx = l[0];
#pragma unroll
  for (int i = 1; i < 16; ++i) mx = fmaxf(mx, l[i]);
#pragma unroll
  for (int o = 32; o > 0; o >>= 1) mx = fmaxf(mx, __shfl_xor(mx, o));
  const float L2E = 1.4426950408889634f;
  float e[16], s = 0.f;
#pragma unroll
  for (int i = 0; i < 16; ++i) { e[i] = exp2f((l[i] - mx) * L2E); s += e[i]; }
#pragma unroll
  for (int o = 32; o > 0; o >>= 1) s += __shfl_xor(s, o);
  float inv = 1.0f / s;
  float4* o4 = reinterpret_cast<float4*>(out + row * S_DIM);
#pragma unroll
  for (int i = 0; i < 4; ++i)
    o4[lane * 4 + i] = make_float4(e[4*i]*inv, e[4*i+1]*inv, e[4*i+2]*inv, e[4*i+3]*inv);
}

extern "C" void kernel_launch(void* const* d_in, const int* in_sizes, int n_in,
                              void* d_out, int out_size, void* d_ws, size_t ws_size,
                              hipStream_t stream) {
  const float* x = (const float*)d_in[0];
  const float* gamma = (const float*)d_in[1];
  float* out = (float*)d_out;
  double* sums = (double*)d_ws;                              // 2 doubles @0
  float* sq = (float*)((char*)d_ws + 256);                   // 16384 floats
  ushort* xb16 = (ushort*)((char*)d_ws + 256 + 65536);       // 16 MB bf16 x
  _Float16* dp = (_Float16*)((char*)d_ws + 256 + 65536 +
                             (size_t)NBATCH * S_DIM * E_DIM * 2);  // 32 MB fp16 d'
  const size_t need_b = 256 + 65536 + (size_t)NBATCH * S_DIM * E_DIM * 2;
  const size_t need_a = need_b + (size_t)NBATCH * S_DIM * S_DIM * 2;

  sqcvt<<<dim3(NBATCH * S_DIM / 4), dim3(256), 0, stream>>>(x, xb16, sq, sums);
  if (ws_size >= need_a) {
    gram9<1><<<dim3(256), dim3(512), 0, stream>>>(xb16, sq, out, dp, sums);
    softmax_f16<<<dim3(NBATCH * S_DIM / 4), dim3(256), 0, stream>>>(dp, out, sums, gamma);
  } else {
    gram9<0><<<dim3(256), dim3(512), 0, stream>>>(xb16, sq, out, dp, sums);
    softmax_f32<<<dim3(NBATCH * S_DIM / 4), dim3(256), 0, stream>>>(out, sums, gamma);
  }
}